// Round 1
// baseline (237.609 us; speedup 1.0000x reference)
//
#include <hip/hip_runtime.h>
#include <hip/hip_bf16.h>

#define B_   8
#define LQ_  2048
#define LK_  2048
#define D_   128
#define QBLK 64
#define KBLK 64
#define NT   (LK_ / KBLK)     // 32 key tiles
#define THREADS 512
#define SCALE 0.08838834764831845f   // 1/sqrt(128)

typedef __attribute__((ext_vector_type(8))) __bf16 bf16x8;   // MFMA A/B frag (4 VGPRs)
typedef __attribute__((ext_vector_type(4))) __bf16 bf16x4;   // 8B LDS write
typedef __attribute__((ext_vector_type(4))) float  f32x4;    // MFMA C/D frag
typedef __attribute__((ext_vector_type(4))) float  fx4;      // global float4 load

// LDS layout (__bf16 units). Row strides padded to multiple of 8 (16B b128 align)
// and chosen so stride mod 32-banks spreads rows (136->68 words = 4 mod 32 etc).
#define QS_OFF 0          // [64][136]  Q tile bf16
#define KS_OFF 8704       // [64][136]  K tile bf16
#define VT_OFF 17408      // [128][72]  V tile TRANSPOSED: Vt[d][k]
#define PS_OFF 26624      // 8 waves x [16][40]  per-wave P tile
#define SMEM_ELEMS 31744  // 63488 B  (< 64KB static LDS)

__global__ __launch_bounds__(THREADS, 2)
void sigattn_kernel(const float* __restrict__ q, const float* __restrict__ k,
                    const float* __restrict__ v, const int* __restrict__ mask,
                    float* __restrict__ out)
{
    __shared__ __bf16 smem[SMEM_ELEMS];

    const int tid  = threadIdx.x;
    const int lane = tid & 63;
    const int wid  = tid >> 6;      // 0..7
    const int qg   = wid & 3;       // q-group: rows [qg*16, qg*16+16)
    const int kg   = wid >> 2;      // key-half: keys [kg*32, kg*32+32) of tile
    const int l15  = lane & 15;
    const int g    = lane >> 4;     // 0..3

    // XCD-friendly mapping: blocks id%8 -> same XCD (round-robin dispatch),
    // so each XCD's 32 blocks share one batch's K/V in its private L2.
    const int bid   = blockIdx.x;
    const int b     = bid & 7;
    const int q0    = (bid >> 3) * QBLK;

    const float* qb = q + (size_t)b * LQ_ * D_ + (size_t)q0 * D_;
    const float* kb = k + (size_t)b * LK_ * D_;
    const float* vb = v + (size_t)b * LK_ * D_;
    const int*   mb = mask + (size_t)b * LQ_ * LK_ + (size_t)q0 * LK_;
    float*       ob = out + (size_t)b * LQ_ * D_ + (size_t)q0 * D_;

    __bf16* Qs = smem + QS_OFF;
    __bf16* Ks = smem + KS_OFF;
    __bf16* Vt = smem + VT_OFF;
    __bf16* Ps = smem + PS_OFF + wid * 640;   // private [16][40]

    const int dv  = tid & 127;   // V-transpose: this thread's d column
    const int kq8 = tid >> 7;    // 0..3 -> key-quad group

    int mcur[8];

    // ---------------- prologue: stage Q + tile 0 ----------------
#pragma unroll
    for (int i = 0; i < 4; ++i) {               // Q: 2048 float4s / 512 thr
        int idx = tid + i * THREADS;
        int row = idx >> 5, c4 = idx & 31;
        fx4 f = *(const fx4*)(qb + row * D_ + c4 * 4);
        bf16x4 w; w[0]=(__bf16)f[0]; w[1]=(__bf16)f[1]; w[2]=(__bf16)f[2]; w[3]=(__bf16)f[3];
        *(bf16x4*)(Qs + row * 136 + c4 * 4) = w;
    }
#pragma unroll
    for (int i = 0; i < 4; ++i) {               // K tile 0
        int idx = tid + i * THREADS;
        int row = idx >> 5, c4 = idx & 31;
        fx4 f = *(const fx4*)(kb + row * D_ + c4 * 4);
        bf16x4 w; w[0]=(__bf16)f[0]; w[1]=(__bf16)f[1]; w[2]=(__bf16)f[2]; w[3]=(__bf16)f[3];
        *(bf16x4*)(Ks + row * 136 + c4 * 4) = w;
    }
#pragma unroll
    for (int i = 0; i < 4; ++i) {               // V tile 0 (transposed store)
        int quad = kq8 + i * 4;
        bf16x4 w;
#pragma unroll
        for (int j = 0; j < 4; ++j) w[j] = (__bf16)vb[(quad * 4 + j) * D_ + dv];
        *(bf16x4*)(Vt + dv * 72 + quad * 4) = w;
    }
#pragma unroll
    for (int n2 = 0; n2 < 2; ++n2)              // mask tile 0 -> regs (C/D order)
#pragma unroll
        for (int r = 0; r < 4; ++r)
            mcur[n2 * 4 + r] = mb[(qg * 16 + 4 * g + r) * LK_ + (kg * 32 + n2 * 16 + l15)];

    __syncthreads();

    // Q fragments: A[i=l15][d contiguous 8 at dblk*32+8g] — held in regs all loop
    bf16x8 qfrag[4];
#pragma unroll
    for (int dblk = 0; dblk < 4; ++dblk)
        qfrag[dblk] = *(const bf16x8*)(Qs + (qg * 16 + l15) * 136 + dblk * 32 + g * 8);

    f32x4 oacc[8];
#pragma unroll
    for (int nb = 0; nb < 8; ++nb) oacc[nb] = (f32x4){0.f, 0.f, 0.f, 0.f};

    // ---------------- main loop over key tiles ----------------
    for (int t = 0; t < NT; ++t) {
        const bool more = (t + 1 < NT);

        // prefetch tile t+1 into registers (latency hidden under compute)
        fx4   kreg[4];
        float vreg[16];
        int   mnxt[8];
        if (more) {
            const int kt = (t + 1) * KBLK;
#pragma unroll
            for (int i = 0; i < 4; ++i) {
                int idx = tid + i * THREADS;
                int row = idx >> 5, c4 = idx & 31;
                kreg[i] = *(const fx4*)(kb + (kt + row) * D_ + c4 * 4);
            }
#pragma unroll
            for (int i = 0; i < 4; ++i) {
                int quad = kq8 + i * 4;
#pragma unroll
                for (int j = 0; j < 4; ++j)
                    vreg[i * 4 + j] = vb[(kt + quad * 4 + j) * D_ + dv];
            }
#pragma unroll
            for (int n2 = 0; n2 < 2; ++n2)
#pragma unroll
                for (int r = 0; r < 4; ++r)
                    mnxt[n2 * 4 + r] = mb[(qg * 16 + 4 * g + r) * LK_ + (kt + kg * 32 + n2 * 16 + l15)];
        }

        // ---- QK^T: S[q][key], wave covers 16 q x 32 keys ----
        f32x4 sacc[2];
        sacc[0] = (f32x4){0.f, 0.f, 0.f, 0.f};
        sacc[1] = (f32x4){0.f, 0.f, 0.f, 0.f};
#pragma unroll
        for (int n2 = 0; n2 < 2; ++n2) {
            const __bf16* krow = Ks + (kg * 32 + n2 * 16 + l15) * 136 + g * 8;
#pragma unroll
            for (int dblk = 0; dblk < 4; ++dblk) {
                bf16x8 bfr = *(const bf16x8*)(krow + dblk * 32);
                sacc[n2] = __builtin_amdgcn_mfma_f32_16x16x32_bf16(qfrag[dblk], bfr, sacc[n2], 0, 0, 0);
            }
        }

        // ---- sigmoid + mask -> P (bf16) into wave-private LDS ----
#pragma unroll
        for (int n2 = 0; n2 < 2; ++n2)
#pragma unroll
            for (int r = 0; r < 4; ++r) {
                float s = sacc[n2][r] * SCALE;
                float p = (mcur[n2 * 4 + r] != 0) ? 0.0f : 1.0f / (1.0f + __expf(-s));
                Ps[(4 * g + r) * 40 + n2 * 16 + l15] = (__bf16)p;
            }

        // ---- PV: out += P(16x32) * V(32x128) ----
        // A-frag: P[q=l15][key 8g..8g+7]  (compiler inserts lgkmcnt wait)
        bf16x8 pfrag = *(const bf16x8*)(Ps + l15 * 40 + g * 8);
#pragma unroll
        for (int nb = 0; nb < 8; ++nb) {
            bf16x8 vfr = *(const bf16x8*)(Vt + (nb * 16 + l15) * 72 + kg * 32 + g * 8);
            oacc[nb] = __builtin_amdgcn_mfma_f32_16x16x32_bf16(pfrag, vfr, oacc[nb], 0, 0, 0);
        }

        __syncthreads();   // everyone done reading K/Vt of tile t

        // ---- write staged tile t+1 to LDS ----
        if (more) {
#pragma unroll
            for (int i = 0; i < 4; ++i) {
                int idx = tid + i * THREADS;
                int row = idx >> 5, c4 = idx & 31;
                bf16x4 w;
                w[0]=(__bf16)kreg[i][0]; w[1]=(__bf16)kreg[i][1];
                w[2]=(__bf16)kreg[i][2]; w[3]=(__bf16)kreg[i][3];
                *(bf16x4*)(Ks + row * 136 + c4 * 4) = w;
            }
#pragma unroll
            for (int i = 0; i < 4; ++i) {
                int quad = kq8 + i * 4;
                bf16x4 w;
#pragma unroll
                for (int j = 0; j < 4; ++j) w[j] = (__bf16)vreg[i * 4 + j];
                *(bf16x4*)(Vt + dv * 72 + quad * 4) = w;
            }
#pragma unroll
            for (int j = 0; j < 8; ++j) mcur[j] = mnxt[j];
        }

        __syncthreads();   // tile t+1 visible before next compute
    }

    // ---------------- epilogue: reduce kg halves, write out ----------------
    float* red = (float*)smem;    // [64][132] f32 overlay (safe: post-barrier)
    if (kg == 0) {
#pragma unroll
        for (int nb = 0; nb < 8; ++nb)
#pragma unroll
            for (int r = 0; r < 4; ++r)
                red[(qg * 16 + 4 * g + r) * 132 + nb * 16 + l15] = oacc[nb][r];
    }
    __syncthreads();
    if (kg == 1) {
#pragma unroll
        for (int nb = 0; nb < 8; ++nb)
#pragma unroll
            for (int r = 0; r < 4; ++r) {
                int row = qg * 16 + 4 * g + r;
                float val = red[row * 132 + nb * 16 + l15] + oacc[nb][r];
                ob[(size_t)row * D_ + nb * 16 + l15] = val;
            }
    }
}

extern "C" void kernel_launch(void* const* d_in, const int* in_sizes, int n_in,
                              void* d_out, int out_size, void* d_ws, size_t ws_size,
                              hipStream_t stream) {
    const float* q    = (const float*)d_in[0];
    const float* k    = (const float*)d_in[1];
    const float* v    = (const float*)d_in[2];
    const int*   mask = (const int*)d_in[3];
    float*       out  = (float*)d_out;

    dim3 grid(B_ * (LQ_ / QBLK));   // 256 blocks
    dim3 block(THREADS);
    sigattn_kernel<<<grid, block, 0, stream>>>(q, k, v, mask, out);
}